// Round 1
// baseline (220.816 us; speedup 1.0000x reference)
//
#include <hip/hip_runtime.h>

#define SEQ_LEN 16384
#define ENC_H   2048
#define DEC_H   2048
#define SCH     128                    // s-chunks for context pass
#define ROWS_PER_CH (SEQ_LEN / SCH)    // 128

// ---------------- Kernel 1: v[e] = sum_d W[e,d] * dec[d] ----------------
// one wave (64 lanes) per output row; block=256 (4 waves); grid=ENC_H/4=512
__global__ void k_wv(const float* __restrict__ W, const float* __restrict__ dec,
                     float* __restrict__ v) {
    const int wave = threadIdx.x >> 6;
    const int lane = threadIdx.x & 63;
    const int row  = blockIdx.x * 4 + wave;
    const float4* Wr = (const float4*)(W + (size_t)row * DEC_H);
    const float4* d4 = (const float4*)dec;
    float acc = 0.f;
#pragma unroll
    for (int k = 0; k < DEC_H / 4 / 64; ++k) {   // 8 float4 per lane
        const int i = k * 64 + lane;
        const float4 w = Wr[i];
        const float4 d = d4[i];
        acc += w.x * d.x + w.y * d.y + w.z * d.z + w.w * d.w;
    }
#pragma unroll
    for (int off = 32; off > 0; off >>= 1) acc += __shfl_down(acc, off, 64);
    if (lane == 0) v[row] = acc;
}

// ---------------- Kernel 2: scores[s] = enc[s] . v ----------------
// v staged in LDS (8 KB); one wave per row; grid-stride over rows
__global__ void k_scores(const float* __restrict__ enc, const float* __restrict__ v,
                         float* __restrict__ scores) {
    __shared__ float4 sv[ENC_H / 4];   // 512 float4 = 8 KB
    const float4* v4 = (const float4*)v;
    for (int i = threadIdx.x; i < ENC_H / 4; i += blockDim.x) sv[i] = v4[i];
    __syncthreads();

    const int wave = threadIdx.x >> 6;
    const int lane = threadIdx.x & 63;
    const int nwaves = gridDim.x * 4;
    for (int row = blockIdx.x * 4 + wave; row < SEQ_LEN; row += nwaves) {
        const float4* er = (const float4*)(enc + (size_t)row * ENC_H);
        float acc = 0.f;
#pragma unroll
        for (int k = 0; k < ENC_H / 4 / 64; ++k) {   // 8 float4 per lane
            const int i = k * 64 + lane;
            const float4 e = er[i];
            const float4 w = sv[i];
            acc += e.x * w.x + e.y * w.y + e.z * w.z + e.w * w.w;
        }
#pragma unroll
        for (int off = 32; off > 0; off >>= 1) acc += __shfl_down(acc, off, 64);
        if (lane == 0) scores[row] = acc;
    }
}

// ---------------- Kernel 3: stable softmax over 16384 scores ----------------
// single block of 1024 threads (16 waves); 16 elements per thread
__global__ void k_softmax(const float* __restrict__ scores, float* __restrict__ weights) {
    __shared__ float red[16];
    const int tid  = threadIdx.x;
    const int lane = tid & 63;
    float loc[16];
    float m = -3.4e38f;
#pragma unroll
    for (int k = 0; k < 16; ++k) {
        loc[k] = scores[k * 1024 + tid];
        m = fmaxf(m, loc[k]);
    }
#pragma unroll
    for (int off = 32; off > 0; off >>= 1) m = fmaxf(m, __shfl_down(m, off, 64));
    if (lane == 0) red[tid >> 6] = m;
    __syncthreads();
    if (tid < 64) {
        float x = (tid < 16) ? red[tid] : -3.4e38f;
#pragma unroll
        for (int off = 8; off > 0; off >>= 1) x = fmaxf(x, __shfl_down(x, off, 64));
        if (tid == 0) red[0] = x;
    }
    __syncthreads();
    m = red[0];
    __syncthreads();   // protect red[] before reuse

    float s = 0.f;
#pragma unroll
    for (int k = 0; k < 16; ++k) {
        loc[k] = expf(loc[k] - m);
        s += loc[k];
    }
#pragma unroll
    for (int off = 32; off > 0; off >>= 1) s += __shfl_down(s, off, 64);
    if (lane == 0) red[tid >> 6] = s;
    __syncthreads();
    if (tid < 64) {
        float x = (tid < 16) ? red[tid] : 0.f;
#pragma unroll
        for (int off = 8; off > 0; off >>= 1) x += __shfl_down(x, off, 64);
        if (tid == 0) red[0] = x;
    }
    __syncthreads();
    const float inv = 1.f / red[0];
#pragma unroll
    for (int k = 0; k < 16; ++k) weights[k * 1024 + tid] = loc[k] * inv;
}

// ---------------- Kernel 4: partial context per s-chunk ----------------
// grid (2, SCH): blockIdx.x = column half (1024 cols), blockIdx.y = s-chunk
// skip chunks whose max weight < 1e-10 (error bound ~1e-5 << 7e-2 threshold)
__global__ void k_ctx_partial(const float* __restrict__ enc,
                              const float* __restrict__ weights,
                              float* __restrict__ partials) {
    __shared__ float sw[ROWS_PER_CH];
    __shared__ int any;
    const int t     = threadIdx.x;
    const int chunk = blockIdx.y;
    if (t == 0) any = 0;
    __syncthreads();
    for (int i = t; i < ROWS_PER_CH; i += 256) {
        const float w = weights[chunk * ROWS_PER_CH + i];
        sw[i] = w;
        if (w > 1e-10f) any = 1;   // benign race (same value)
    }
    __syncthreads();

    const int col4 = blockIdx.x * 256 + t;           // float4 column index
    float4* p4 = (float4*)partials;
    if (!any) {
        const float4 z = {0.f, 0.f, 0.f, 0.f};
        p4[(size_t)chunk * (ENC_H / 4) + col4] = z;
        return;
    }
    const float4* e4 = (const float4*)enc;
    float4 acc = {0.f, 0.f, 0.f, 0.f};
    const int base_row = chunk * ROWS_PER_CH;
    for (int r = 0; r < ROWS_PER_CH; ++r) {
        const float w  = sw[r];
        const float4 e = e4[(size_t)(base_row + r) * (ENC_H / 4) + col4];
        acc.x += w * e.x;
        acc.y += w * e.y;
        acc.z += w * e.z;
        acc.w += w * e.w;
    }
    p4[(size_t)chunk * (ENC_H / 4) + col4] = acc;
}

// ---------------- Kernel 5: reduce partials -> out ----------------
__global__ void k_ctx_reduce(const float* __restrict__ partials, float* __restrict__ out) {
    const int e = blockIdx.x * 256 + threadIdx.x;    // 8 blocks x 256 = 2048
    float acc = 0.f;
    for (int c = 0; c < SCH; ++c) acc += partials[(size_t)c * ENC_H + e];
    out[e] = acc;
}

extern "C" void kernel_launch(void* const* d_in, const int* in_sizes, int n_in,
                              void* d_out, int out_size, void* d_ws, size_t ws_size,
                              hipStream_t stream) {
    const float* enc = (const float*)d_in[0];   // [16384, 2048]
    const float* dec = (const float*)d_in[1];   // [1, 2048]
    const float* W   = (const float*)d_in[2];   // [2048, 2048]
    float* out = (float*)d_out;                 // [1, 2048]

    float* ws       = (float*)d_ws;
    float* v        = ws;                        // 2048
    float* scores   = v + ENC_H;                 // 16384
    float* weights  = scores + SEQ_LEN;          // 16384
    float* partials = weights + SEQ_LEN;         // 128 * 2048

    k_wv<<<ENC_H / 4, 256, 0, stream>>>(W, dec, v);
    k_scores<<<1024, 256, 0, stream>>>(enc, v, scores);
    k_softmax<<<1, 1024, 0, stream>>>(scores, weights);
    k_ctx_partial<<<dim3(2, SCH), 256, 0, stream>>>(enc, weights, partials);
    k_ctx_reduce<<<ENC_H / 256, 256, 0, stream>>>(partials, out);
}

// Round 2
// 209.846 us; speedup vs baseline: 1.0523x; 1.0523x over previous
//
#include <hip/hip_runtime.h>

#define SEQ_LEN 16384
#define ENC_H   2048
#define DEC_H   2048
#define NB_SC   1024                 // k_scores blocks (16 rows each)
#define NB_CTX  256                  // k_ctx blocks
#define CHUNK   (SEQ_LEN / NB_CTX)   // 64 rows per ctx block
#define WTHR    1e-9f                // skip threshold; err <= 16384*1e-9*max|enc| ~ 1e-4

// ---------------- K1: v = W @ dec ; also zero d_out ----------------
// one wave per row of W; grid=512 x 256
__global__ __launch_bounds__(256) void k_wv(const float* __restrict__ W,
                                            const float* __restrict__ dec,
                                            float* __restrict__ v,
                                            float* __restrict__ out) {
    if (blockIdx.x < ENC_H / 256) out[blockIdx.x * 256 + threadIdx.x] = 0.f;
    const int wave = threadIdx.x >> 6, lane = threadIdx.x & 63;
    const int row  = blockIdx.x * 4 + wave;
    const float4* Wr = (const float4*)(W + (size_t)row * DEC_H);
    const float4* d4 = (const float4*)dec;
    float acc = 0.f;
#pragma unroll
    for (int k = 0; k < DEC_H / 4 / 64; ++k) {     // 8 float4 per lane
        const int i = k * 64 + lane;
        const float4 w = Wr[i], d = d4[i];
        acc += w.x * d.x + w.y * d.y + w.z * d.z + w.w * d.w;
    }
#pragma unroll
    for (int off = 32; off > 0; off >>= 1) acc += __shfl_down(acc, off, 64);
    if (lane == 0) v[row] = acc;
}

// ------- K2: scores[s] = enc[s].v  + per-block online-softmax state -------
// grid=1024 x 256; each wave does 4 rows; block covers 16 rows total
__global__ __launch_bounds__(256) void k_scores(const float* __restrict__ enc,
                                                const float* __restrict__ v,
                                                float* __restrict__ scores,
                                                float* __restrict__ bmax,
                                                float* __restrict__ bsum) {
    __shared__ float4 sv[ENC_H / 4];   // 8 KB
    __shared__ float smax[4], ssum[4];
    const float4* v4 = (const float4*)v;
    for (int i = threadIdx.x; i < ENC_H / 4; i += 256) sv[i] = v4[i];
    __syncthreads();

    const int wave = threadIdx.x >> 6, lane = threadIdx.x & 63;
    const int nw = gridDim.x * 4;
    float lm = -3.4e38f, lvals[4];
    int nv = 0;
    for (int row = blockIdx.x * 4 + wave; row < SEQ_LEN; row += nw) {
        const float4* er = (const float4*)(enc + (size_t)row * ENC_H);
        float acc = 0.f;
#pragma unroll
        for (int k = 0; k < ENC_H / 4 / 64; ++k) {
            const int i = k * 64 + lane;
            const float4 e = er[i], w = sv[i];
            acc += e.x * w.x + e.y * w.y + e.z * w.z + e.w * w.w;
        }
#pragma unroll
        for (int off = 32; off > 0; off >>= 1) acc += __shfl_down(acc, off, 64);
        if (lane == 0) { scores[row] = acc; lvals[nv++] = acc; lm = fmaxf(lm, acc); }
    }
    if (lane == 0) {                       // wave-local expsum at wave-local max
        float ls = 0.f;
        for (int k = 0; k < nv; ++k) ls += __expf(lvals[k] - lm);
        smax[wave] = lm; ssum[wave] = ls;
    }
    __syncthreads();
    if (threadIdx.x == 0) {                // combine 4 waves -> block state
        float bm = fmaxf(fmaxf(smax[0], smax[1]), fmaxf(smax[2], smax[3]));
        float bs = 0.f;
        for (int w2 = 0; w2 < 4; ++w2) bs += ssum[w2] * __expf(smax[w2] - bm);
        bmax[blockIdx.x] = bm; bsum[blockIdx.x] = bs;
    }
}

// ------- K3: softmax finalize + sparse context accumulation -------
// grid=256 x 256; block b owns rows [b*64, b*64+64); skips if all weights tiny
__global__ __launch_bounds__(256) void k_ctx(const float* __restrict__ enc,
                                             const float* __restrict__ scores,
                                             const float* __restrict__ bmax,
                                             const float* __restrict__ bsum,
                                             float* __restrict__ out) {
    __shared__ float sred[4], sred2[4], sw[CHUNK];
    const int t = threadIdx.x, lane = t & 63, wave = t >> 6;

    // global max over 1024 block maxes
    float m = fmaxf(fmaxf(bmax[t], bmax[t + 256]), fmaxf(bmax[t + 512], bmax[t + 768]));
#pragma unroll
    for (int off = 32; off > 0; off >>= 1) m = fmaxf(m, __shfl_down(m, off, 64));
    if (lane == 0) sred[wave] = m;
    __syncthreads();
    m = fmaxf(fmaxf(sred[0], sred[1]), fmaxf(sred[2], sred[3]));

    // global denom via rescaled block sums
    float s = bsum[t]       * __expf(bmax[t]       - m)
            + bsum[t + 256] * __expf(bmax[t + 256] - m)
            + bsum[t + 512] * __expf(bmax[t + 512] - m)
            + bsum[t + 768] * __expf(bmax[t + 768] - m);
#pragma unroll
    for (int off = 32; off > 0; off >>= 1) s += __shfl_down(s, off, 64);
    if (lane == 0) sred2[wave] = s;
    __syncthreads();
    const float inv = 1.f / (sred2[0] + sred2[1] + sred2[2] + sred2[3]);

    // this block's chunk weights
    const int b = blockIdx.x;
    if (t < CHUNK) sw[t] = __expf(scores[b * CHUNK + t] - m) * inv;
    __syncthreads();
    float wmax = 0.f;
    for (int r = 0; r < CHUNK; ++r) wmax = fmaxf(wmax, sw[r]);
    if (wmax <= WTHR) return;              // uniform exit: chunk contributes < 1e-4

    const float4* e4 = (const float4*)enc;
    float4 a0 = {0.f, 0.f, 0.f, 0.f}, a1 = {0.f, 0.f, 0.f, 0.f};
    const size_t base = (size_t)b * CHUNK * (ENC_H / 4);
    for (int r = 0; r < CHUNK; ++r) {
        const float w = sw[r];
        if (w <= WTHR) continue;           // uniform across block
        const float4 e0 = e4[base + (size_t)r * (ENC_H / 4) + t];
        const float4 e1 = e4[base + (size_t)r * (ENC_H / 4) + t + 256];
        a0.x += w * e0.x; a0.y += w * e0.y; a0.z += w * e0.z; a0.w += w * e0.w;
        a1.x += w * e1.x; a1.y += w * e1.y; a1.z += w * e1.z; a1.w += w * e1.w;
    }
    atomicAdd(&out[4 * t + 0], a0.x);
    atomicAdd(&out[4 * t + 1], a0.y);
    atomicAdd(&out[4 * t + 2], a0.z);
    atomicAdd(&out[4 * t + 3], a0.w);
    atomicAdd(&out[4 * (t + 256) + 0], a1.x);
    atomicAdd(&out[4 * (t + 256) + 1], a1.y);
    atomicAdd(&out[4 * (t + 256) + 2], a1.z);
    atomicAdd(&out[4 * (t + 256) + 3], a1.w);
}

extern "C" void kernel_launch(void* const* d_in, const int* in_sizes, int n_in,
                              void* d_out, int out_size, void* d_ws, size_t ws_size,
                              hipStream_t stream) {
    const float* enc = (const float*)d_in[0];   // [16384, 2048]
    const float* dec = (const float*)d_in[1];   // [1, 2048]
    const float* W   = (const float*)d_in[2];   // [2048, 2048]
    float* out = (float*)d_out;                 // [1, 2048]

    float* ws      = (float*)d_ws;
    float* v       = ws;                  // 2048
    float* scores  = v + ENC_H;           // 16384
    float* bmax    = scores + SEQ_LEN;    // 1024
    float* bsum    = bmax + NB_SC;        // 1024

    k_wv    <<<ENC_H / 4, 256, 0, stream>>>(W, dec, v, out);
    k_scores<<<NB_SC,     256, 0, stream>>>(enc, v, scores, bmax, bsum);
    k_ctx   <<<NB_CTX,    256, 0, stream>>>(enc, scores, bmax, bsum, out);
}